// Round 1
// baseline (634.652 us; speedup 1.0000x reference)
//
#include <hip/hip_runtime.h>
#include <cstdint>
#include <cstddef>

constexpr int BB  = 32;
constexpr int TT  = 384;
constexpr int MM  = 1536;
constexpr int RPT = 6;            // rows per lane = 384/64
constexpr int W32 = MM / 32;      // 48 bit-words per row
constexpr float NEGV = -1.0e7f;

// workspace layout (bytes)
constexpr size_t WS_BITS_OFF = 0;
constexpr size_t WS_BITS_SZ  = (size_t)BB * TT * W32 * 4;   // 2,359,296
constexpr size_t WS_A_OFF    = WS_BITS_OFF + WS_BITS_SZ;
constexpr size_t WS_A_SZ     = (size_t)BB * 512 * 4;        // A[b][0..384] (stride 512)
constexpr size_t WS_LEN_OFF  = WS_A_OFF + WS_A_SZ;          // int t_len,m_len per sample

// ---------------- forward Viterbi DP: emit 1 backpointer bit per cell ----------------
__global__ __launch_bounds__(64) void mas_forward(
    const float* __restrict__ log_p, const float* __restrict__ mask,
    uint32_t* __restrict__ bits, int* __restrict__ lens)
{
#pragma clang fp contract(off)
  const int b = blockIdx.x;
  const int k = threadIdx.x;
  const float* lp = log_p + (size_t)b * TT * MM;
  const float* mk = mask  + (size_t)b * TT * MM;

  // lengths from mask (t_len = sum_t mask[t][0], m_len = sum_j mask[0][j])
  float ts = 0.f, ms = 0.f;
  for (int t = k; t < TT; t += 64) ts += mk[(size_t)t * MM];
  for (int j = k; j < MM; j += 64) ms += mk[j];
#pragma unroll
  for (int off = 32; off >= 1; off >>= 1) {
    ts += __shfl_xor(ts, off);
    ms += __shfl_xor(ms, off);
  }
  const int t_len = (int)ts;
  const int m_len = (int)ms;
  if (k == 0) { lens[b * 2 + 0] = t_len; lens[b * 2 + 1] = m_len; }

  const int r0 = k * RPT;          // first global row owned by this lane
  float qp[RPT];
  uint32_t bacc[RPT];
#pragma unroll
  for (int i = 0; i < RPT; ++i) { qp[i] = NEGV; bacc[i] = 0u; }

  // 4-deep ring of float4 column-groups (4 columns each), prefetch distance 2
  float4 lbuf[4][RPT], mbuf[4][RPT];
#pragma unroll
  for (int g = 0; g < 2; ++g)
#pragma unroll
    for (int i = 0; i < RPT; ++i) {
      lbuf[g][i] = *(const float4*)(lp + (size_t)(r0 + i) * MM + g * 4);
      mbuf[g][i] = *(const float4*)(mk + (size_t)(r0 + i) * MM + g * 4);
    }

  uint32_t* bitp = bits + ((size_t)b * TT + r0) * W32;

  int j = 0;
  for (int w = 0; w < W32; ++w) {
#pragma unroll
    for (int g8 = 0; g8 < 8; ++g8) {
      const int cb = g8 & 3;             // current buffer (w*8 ≡ 0 mod 4)
      const int pb = (g8 + 2) & 3;       // prefetch buffer
      {
        int gp = w * 8 + g8 + 2;
        if (gp > MM / 4 - 1) gp = MM / 4 - 1;
#pragma unroll
        for (int i = 0; i < RPT; ++i) {
          lbuf[pb][i] = *(const float4*)(lp + (size_t)(r0 + i) * MM + (size_t)gp * 4);
          mbuf[pb][i] = *(const float4*)(mk + (size_t)(r0 + i) * MM + (size_t)gp * 4);
        }
      }
#pragma unroll
      for (int u = 0; u < 4; ++u, ++j) {
        // boundary value Q[r0-1][j-1] from lane k-1 (issued early, used last)
        float qlast = __shfl_up(qp[RPT - 1], 1);
        if (k == 0) qlast = (j == 0) ? 0.0f : NEGV;   // global row 0 'advance' rule
        const uint32_t mbit = 1u << (j & 31);
        // descending rows so qp[i-1] is still the previous column's value;
        // row 0 last => shuffle latency hidden
#pragma unroll
        for (int i = RPT - 1; i >= 0; --i) {
          const float stay = qp[i];
          const float adv  = (i == 0) ? qlast : qp[i - 1];
          const float lv = (&lbuf[cb][i].x)[u];
          const float mv = (&mbuf[cb][i].x)[u];
          const float x  = lv * mv;                    // contract(off): no fma
          const float q  = x + fmaxf(stay, adv);
          if (stay < adv) bacc[i] |= mbit;             // backtrack 'dec' bit
          qp[i] = q;
        }
      }
    }
    // flush 32 columns of bits, row-major
#pragma unroll
    for (int i = 0; i < RPT; ++i) {
      bitp[(size_t)i * W32 + w] = bacc[i];
      bacc[i] = 0u;
    }
  }
}

// ---------------- backtrack: one walker per sample -> per-row interval starts A[t] ----------------
__global__ __launch_bounds__(64) void mas_backtrack(
    const uint32_t* __restrict__ bits, const int* __restrict__ lens,
    int* __restrict__ A)
{
  const int b = blockIdx.x;
  const int k = threadIdx.x;
  const int t_len = lens[b * 2 + 0];
  const int m_len = lens[b * 2 + 1];
  int* Ab = A + b * 512;
  for (int t = k; t <= TT; t += 64) Ab[t] = (t >= t_len) ? m_len : 0;
  __syncthreads();
  if (k != 0) return;
  if (t_len <= 1 || m_len <= 0) return;   // path is row 0 everywhere; A already correct

  const uint32_t* bb = bits + (size_t)b * TT * W32;
  int t = t_len - 1;
  int w = (m_len - 1) >> 5;
  uint32_t cur    = bb[t * W32 + w];
  uint32_t below  = (t >= 1) ? bb[(t - 1) * W32 + w] : 0u;
  uint32_t below2 = (t >= 2) ? bb[(t - 2) * W32 + w] : 0u;

  for (int j = m_len - 1; j >= 1; --j) {
    if ((cur >> (j & 31)) & 1u) {        // dec: column j-1 belongs to row t-1
      Ab[t] = j;
      --t;
      cur = below;
      below = below2;
      below2 = (t >= 2) ? bb[(t - 2) * W32 + w] : 0u;
      if (t == 0) break;                 // row-0 bits are always 0; A[0]=0 preset
    }
    if ((j & 31) == 0 && j > 1) {        // crossing into the next 32-column window
      --w;
      cur    = bb[t * W32 + w];
      below  = (t >= 1) ? bb[(t - 1) * W32 + w] : 0u;
      below2 = (t >= 2) ? bb[(t - 2) * W32 + w] : 0u;
    }
  }
}

// ---------------- fill: out[b][t][j] = 1 iff A[t] <= j < A[t+1] ----------------
__global__ __launch_bounds__(256) void mas_fill(
    const int* __restrict__ A, float* __restrict__ out)
{
  const int idx = blockIdx.x * 256 + threadIdx.x;   // over B*T*(M/4)
  const int nj4 = MM / 4;                           // 384
  const int j4 = (idx % nj4) * 4;
  const int t  = (idx / nj4) % TT;
  const int b  = idx / (nj4 * TT);
  const int a  = A[b * 512 + t];
  const int e  = A[b * 512 + t + 1];
  float4 v;
  v.x = (j4 + 0 >= a && j4 + 0 < e) ? 1.0f : 0.0f;
  v.y = (j4 + 1 >= a && j4 + 1 < e) ? 1.0f : 0.0f;
  v.z = (j4 + 2 >= a && j4 + 2 < e) ? 1.0f : 0.0f;
  v.w = (j4 + 3 >= a && j4 + 3 < e) ? 1.0f : 0.0f;
  reinterpret_cast<float4*>(out)[idx] = v;
}

extern "C" void kernel_launch(void* const* d_in, const int* in_sizes, int n_in,
                              void* d_out, int out_size, void* d_ws, size_t ws_size,
                              hipStream_t stream) {
  const float* log_p = (const float*)d_in[0];
  const float* maskp = (const float*)d_in[1];
  float* out = (float*)d_out;
  uint32_t* bits = (uint32_t*)((char*)d_ws + WS_BITS_OFF);
  int* A    = (int*)((char*)d_ws + WS_A_OFF);
  int* lens = (int*)((char*)d_ws + WS_LEN_OFF);

  mas_forward<<<BB, 64, 0, stream>>>(log_p, maskp, bits, lens);
  mas_backtrack<<<BB, 64, 0, stream>>>(bits, lens, A);
  mas_fill<<<(BB * TT * (MM / 4)) / 256, 256, 0, stream>>>(A, out);
}